// Round 8
// baseline (34.098 us; speedup 1.0000x reference)
//
#include <hip/hip_runtime.h>

// ROIAlign (aligned=True, TF crop_and_resize semantics), NHWC fp32.
// inputs: [2,100,100,256] f32; boxes: [1024,4] f32 (x0,y0,x1,y1);
// box_inds: [1024] i32; out: [1024,7,7,256] f32.
//
// Round-8 structure (3 kernels):
//  A  sort_boxes: ballot-sort 1024 boxes by (image*4 + y-band) -> perm
//                 (XCD L2 locality). Parallel Hillis-Steele scan.
//  A2 meta:       per sorted slot, per output row/col: fold the 2 samples'
//                 bilinear footprints + index-clamp + validity into a
//                 CONTIGUOUS range [c0, c0+n), n<=4, with zero-padded
//                 weights. Rows: absolute offsets (image base folded),
//                 weights x0.25; n packed in low bits.
//  B  main:       ONE WAVE PER HALF OUTPUT ROW (14336 waves). Columns are
//                 consumed in nondecreasing order; a mod-4 register ring
//                 holds the last 4 columns x NR rows, so each unique column
//                 of the row is loaded ONCE (~-30% gather traffic vs
//                 per-pixel dedup). Weights permute to ring slots via a
//                 4-case uniform switch on c0&3; FMA is unconditional 4xNR
//                 (stale slots see weight 0; ring zero-initialized).

constexpr int   H_IN  = 100;
constexpr int   W_IN  = 100;
constexpr int   C_IN  = 256;
constexpr int   OUT_H = 7;
constexpr int   OUT_W = 7;
constexpr int   NPIX  = OUT_H * OUT_W;   // 49
constexpr int   NBOX  = 1024;
constexpr float SCALE = 0.125f;

typedef float f32x4 __attribute__((ext_vector_type(4)));

struct Meta { int4 off; float4 w; };     // off.x = packed; off.y/z/w unused

// ws layout: perm int[1024] @0 ; rmeta Meta[7168] @4096 ; cmeta Meta[7168]
constexpr int RMETA_OFF = 4096;
constexpr int CMETA_OFF = 4096 + 7168 * 32;

// ---------------- kernel A: spatial box sort (1 block, 1024 threads) -------
__global__ __launch_bounds__(1024) void sort_boxes_kernel(
    const float* __restrict__ boxes,
    const int*   __restrict__ box_inds,
    int*         __restrict__ perm)
{
    const int tid  = threadIdx.x;
    const int wave = tid >> 6;
    const int lane = tid & 63;

    const float y0 = boxes[tid * 4 + 1] * SCALE;
    const float y1 = boxes[tid * 4 + 3] * SCALE;
    const float cy = 0.5f * (y0 + y1);
    int band = (int)(cy * (1.0f / 25.0f));
    band = min(max(band, 0), 3);
    const int bin = box_inds[tid] * 4 + band;   // 0..7

    __shared__ int whist[16][8];
    __shared__ int sc[129];        // exclusive scan, bin-major (k*16 + w)

    int wrank = 0;
    const unsigned long long ltmask = (lane == 63) ? ~0ull >> 1
                                                   : (1ull << lane) - 1;
#pragma unroll
    for (int k = 0; k < 8; ++k) {
        const unsigned long long bal = __ballot(bin == k);
        if (bin == k) wrank = __popcll(bal & ltmask);
        if (lane == 0) whist[wave][k] = __popcll(bal);
    }
    __syncthreads();

    if (tid < 128) sc[tid + 1] = whist[tid & 15][tid >> 4];
    if (tid == 0)  sc[0] = 0;
    __syncthreads();
    // Hillis-Steele inclusive scan over sc[1..128]
    for (int off = 1; off < 128; off <<= 1) {
        int v = 0;
        if (tid < 128 && tid >= off) v = sc[tid - off + 1];
        __syncthreads();
        if (tid < 128 && tid >= off) sc[tid + 1] += v;
        __syncthreads();
    }

    perm[sc[bin * 16 + wave] + wrank] = tid;
}

// ---------------- contiguous fold of 2 bilinear samples --------------------
// Reference semantics: sample valid iff coord in [0, LIM-1]; indices are
// floor / floor+1 clamped to [0, LIM-1] (for valid samples only the top
// clamp at exactly LIM-1 can trigger). Output: contiguous [c0, c0+n), n<=4,
// weights w[0..3] (zero-padded), invalid samples contribute 0.
__device__ __forceinline__ void fold_dim(float s0, float step, int LIM,
                                         int& c0, int& n, float* w)
{
    float s[2] = { s0, s0 + step };
    int   fl[2]; float t[2]; bool val[2];
    int lo = 0x7fffffff, hi = -0x7fffffff;
#pragma unroll
    for (int k = 0; k < 2; ++k) {
        const float f = floorf(s[k]);
        fl[k]  = (int)f;
        t[k]   = s[k] - f;
        val[k] = (s[k] >= 0.0f && s[k] <= (float)(LIM - 1));
        if (val[k]) {
            lo = min(lo, fl[k]);
            hi = max(hi, min(fl[k] + 1, LIM - 1));
        }
    }
    w[0] = w[1] = w[2] = w[3] = 0.0f;
    if (lo > hi) {                     // no valid sample: degenerate, weight 0
        c0 = min(max(fl[0], 0), LIM - 1);
        n  = 1;
        return;
    }
    c0 = lo;
    n  = hi - lo + 1;                  // <= 4 (step <= 1.79)
#pragma unroll
    for (int k = 0; k < 2; ++k) {
        if (val[k]) {
            w[fl[k] - lo]                    += 1.0f - t[k];
            w[min(fl[k] + 1, LIM - 1) - lo]  += t[k];
        }
    }
}

// ---------------- kernel A2: per-slot metadata (56 blocks x 256) -----------
__global__ __launch_bounds__(256) void meta_kernel(
    const float* __restrict__ boxes,
    const int*   __restrict__ box_inds,
    const int*   __restrict__ perm,
    Meta*        __restrict__ rmeta,
    Meta*        __restrict__ cmeta)
{
    const int t = blockIdx.x * 256 + threadIdx.x;   // 0..14335
    if (t >= NBOX * 14) return;
    const int slot = t / 14;
    const int d    = t - slot * 14;

    const int b = perm[slot];
    const int n = box_inds[b];

    const float bx0 = boxes[b * 4 + 0] * SCALE;
    const float by0 = boxes[b * 4 + 1] * SCALE;
    const float bx1 = boxes[b * 4 + 2] * SCALE;
    const float by1 = boxes[b * 4 + 3] * SCALE;
    const float sw  = (bx1 - bx0) * (1.0f / 14.0f);
    const float sh  = (by1 - by0) * (1.0f / 14.0f);

    int c0, cnt; float wgt[4];
    Meta m;
    m.off.y = m.off.z = m.off.w = 0;
    if (d < 7) {                       // row meta for oy = d
        const float s0 = by0 + sh * ((float)(d * 2) + 0.5f) - 0.5f;
        fold_dim(s0, sh, H_IN, c0, cnt, wgt);
        // absolute element offset of first row, image base folded; nr-1 packed
        m.off.x = (n * (H_IN * W_IN * C_IN) + c0 * (W_IN * C_IN)) | (cnt - 1);
        m.w.x = wgt[0] * 0.25f; m.w.y = wgt[1] * 0.25f;
        m.w.z = wgt[2] * 0.25f; m.w.w = wgt[3] * 0.25f;
        rmeta[slot * 7 + d] = m;
    } else {                           // col meta for ox = d-7
        const int ox = d - 7;
        const float s0 = bx0 + sw * ((float)(ox * 2) + 0.5f) - 0.5f;
        fold_dim(s0, sw, W_IN, c0, cnt, wgt);
        m.off.x = (c0 << 3) | cnt;
        m.w.x = wgt[0]; m.w.y = wgt[1]; m.w.z = wgt[2]; m.w.w = wgt[3];
        cmeta[slot * 7 + ox] = m;
    }
}

// ---------------- kernel B: one wave per half output row -------------------
template<int NR>
__device__ __forceinline__ void process_half(
    const float* __restrict__ inputs,
    const Meta*  __restrict__ cmeta,
    float*       __restrict__ out,
    int slotbase, int r0off, const float* wr,
    int b, int oy, int ox0, int npx, int c4)
{
    f32x4 ring[4][NR];
#pragma unroll
    for (int s = 0; s < 4; ++s)
#pragma unroll
        for (int r = 0; r < NR; ++r)
            ring[s][r] = f32x4{0.f, 0.f, 0.f, 0.f};

    int L = -1000000;                  // cols loaded up to (exclusive)

    for (int j = 0; j < npx; ++j) {
        const int ox = ox0 + j;
        const Meta cm = cmeta[slotbase + ox];        // 32 B uniform load
        const int pk = __builtin_amdgcn_readfirstlane(cm.off.x);
        const int c0 = pk >> 3;
        const int nc = pk & 7;
        const int lo = max(L, c0);
        const int hi = c0 + nc;

        // load only NEW columns, each into ring slot col&3 (static regs)
#pragma unroll
        for (int s = 0; s < 4; ++s) {
            const int cs = lo + ((s - lo) & 3);
            if (cs < hi) {                           // wave-uniform branch
                const int cb = r0off + cs * C_IN + c4;
#pragma unroll
                for (int r = 0; r < NR; ++r)
                    ring[s][r] = *(const f32x4*)(inputs + cb + r * (W_IN * C_IN));
            }
        }
        L = hi > L ? hi : L;

        // permute pixel weights to ring slots: slot s gets w[(s-c0)&3]
        const float w0 = cm.w.x, w1 = cm.w.y, w2 = cm.w.z, w3 = cm.w.w;
        float ws0, ws1, ws2, ws3;
        switch (c0 & 3) {
            case 0:  ws0 = w0; ws1 = w1; ws2 = w2; ws3 = w3; break;
            case 1:  ws0 = w3; ws1 = w0; ws2 = w1; ws3 = w2; break;
            case 2:  ws0 = w2; ws1 = w3; ws2 = w0; ws3 = w1; break;
            default: ws0 = w1; ws1 = w2; ws2 = w3; ws3 = w0; break;
        }

        f32x4 acc = {0.f, 0.f, 0.f, 0.f};
#pragma unroll
        for (int r = 0; r < NR; ++r) {
            acc += ring[0][r] * (wr[r] * ws0);
            acc += ring[1][r] * (wr[r] * ws1);
            acc += ring[2][r] * (wr[r] * ws2);
            acc += ring[3][r] * (wr[r] * ws3);
        }

        float* op = out + ((size_t)b * NPIX + oy * OUT_W + ox) * C_IN + c4;
        __builtin_nontemporal_store(acc, (f32x4*)op);
    }
}

__global__ __launch_bounds__(256) void roi_align_kernel(
    const float* __restrict__ inputs,
    const int*   __restrict__ perm,
    const Meta*  __restrict__ rmeta,
    const Meta*  __restrict__ cmeta,
    float*       __restrict__ out)
{
    const int lane = threadIdx.x & 63;
    const int wv   = threadIdx.x >> 6;

    // XCD-chunked swizzle: grid = 3584 (div by 8); 448 blocks = 128 sorted
    // slots per XCD chunk.
    const int nchunk = gridDim.x >> 3;
    const int lbid   = (blockIdx.x & 7) * nchunk + (blockIdx.x >> 3);
    const int wgid   = lbid * 4 + wv;            // half-row id [0, 14336)

    const int slot = wgid / 14;
    const int d    = wgid - slot * 14;
    const int oy   = d >> 1;
    const int half = d & 1;
    const int ox0  = half ? 4 : 0;
    const int npx  = half ? 3 : 4;

    const int b = __builtin_amdgcn_readfirstlane(perm[slot]);

    const Meta rm = rmeta[slot * 7 + oy];        // 32 B uniform load
    const int rpk   = __builtin_amdgcn_readfirstlane(rm.off.x);
    const int nrm1  = rpk & 3;
    const int r0off = rpk & ~3;
    const float wr[4] = { rm.w.x, rm.w.y, rm.w.z, rm.w.w };

    const int c4 = lane * 4;
    const int slotbase = slot * 7;

    switch (nrm1) {
        case 0:  process_half<1>(inputs, cmeta, out, slotbase, r0off, wr, b, oy, ox0, npx, c4); break;
        case 1:  process_half<2>(inputs, cmeta, out, slotbase, r0off, wr, b, oy, ox0, npx, c4); break;
        case 2:  process_half<3>(inputs, cmeta, out, slotbase, r0off, wr, b, oy, ox0, npx, c4); break;
        default: process_half<4>(inputs, cmeta, out, slotbase, r0off, wr, b, oy, ox0, npx, c4); break;
    }
}

extern "C" void kernel_launch(void* const* d_in, const int* in_sizes, int n_in,
                              void* d_out, int out_size, void* d_ws, size_t ws_size,
                              hipStream_t stream) {
    const float* inputs   = (const float*)d_in[0];
    const float* boxes    = (const float*)d_in[1];
    const int*   box_inds = (const int*)d_in[2];
    float*       out      = (float*)d_out;

    int*  perm  = (int*)d_ws;
    Meta* rmeta = (Meta*)((char*)d_ws + RMETA_OFF);
    Meta* cmeta = (Meta*)((char*)d_ws + CMETA_OFF);

    sort_boxes_kernel<<<1, NBOX, 0, stream>>>(boxes, box_inds, perm);
    meta_kernel<<<56, 256, 0, stream>>>(boxes, box_inds, perm, rmeta, cmeta);

    const int blocks = NBOX * 14 / 4;            // 3584
    roi_align_kernel<<<blocks, 256, 0, stream>>>(inputs, perm, rmeta, cmeta, out);
}

// Round 9
// 33.140 us; speedup vs baseline: 1.0289x; 1.0289x over previous
//
#include <hip/hip_runtime.h>

// ROIAlign (aligned=True, TF crop_and_resize semantics), NHWC fp32.
// inputs: [2,100,100,256] f32; boxes: [1024,4] f32 (x0,y0,x1,y1);
// box_inds: [1024] i32; out: [1024,7,7,256] f32.
//
// Round-9 structure (3 kernels):
//  A  sort_boxes: ballot-sort 1024 boxes by (image*4 + y-band) -> perm
//                 (XCD L2 locality).
//  A2 pmeta:      per OUTPUT PIXEL (50176), one 48 B record:
//                 { base  = absolute element offset (image + r0 + c0 folded;
//                           both dims folded to CONTIGUOUS ranges),
//                   oute  = output element offset (perm folded in),
//                   sel   = (nr-1)*4 + (nc-1),
//                   wr[4] (x0.25), wc[4] (zero-padded) }.
//                 Corner (i,j) = base + i*25600 + j*256: compile-time offsets,
//                 zero per-corner address math in the main kernel.
//  B  main:       one wave per pixel (50176 waves). Block = 4 pixels; one
//                 cooperative 192 B meta load -> LDS -> barrier; per wave:
//                 LDS broadcast reads, readfirstlane(sel), switch ->
//                 NR*NC back-to-back const-offset loads, FMA, NT store.

constexpr int   H_IN  = 100;
constexpr int   W_IN  = 100;
constexpr int   C_IN  = 256;
constexpr int   OUT_H = 7;
constexpr int   OUT_W = 7;
constexpr int   NPIX  = OUT_H * OUT_W;   // 49
constexpr int   NBOX  = 1024;
constexpr float SCALE = 0.125f;

typedef float f32x4 __attribute__((ext_vector_type(4)));

// ws layout: perm int[1024] @0 ; pmeta int[50176*12] @4096 (2.41 MB)
constexpr int PMETA_OFF = 4096;

// ---------------- kernel A: spatial box sort (1 block, 1024 threads) -------
__global__ __launch_bounds__(1024) void sort_boxes_kernel(
    const float* __restrict__ boxes,
    const int*   __restrict__ box_inds,
    int*         __restrict__ perm)
{
    const int tid  = threadIdx.x;
    const int wave = tid >> 6;
    const int lane = tid & 63;

    const float y0 = boxes[tid * 4 + 1] * SCALE;
    const float y1 = boxes[tid * 4 + 3] * SCALE;
    const float cy = 0.5f * (y0 + y1);
    int band = (int)(cy * (1.0f / 25.0f));
    band = min(max(band, 0), 3);
    const int bin = box_inds[tid] * 4 + band;   // 0..7

    __shared__ int whist[16][8];
    __shared__ int sc[129];        // exclusive scan, bin-major (k*16 + w)

    int wrank = 0;
    const unsigned long long ltmask = (lane == 63) ? ~0ull >> 1
                                                   : (1ull << lane) - 1;
#pragma unroll
    for (int k = 0; k < 8; ++k) {
        const unsigned long long bal = __ballot(bin == k);
        if (bin == k) wrank = __popcll(bal & ltmask);
        if (lane == 0) whist[wave][k] = __popcll(bal);
    }
    __syncthreads();

    if (tid < 128) sc[tid + 1] = whist[tid & 15][tid >> 4];
    if (tid == 0)  sc[0] = 0;
    __syncthreads();
    // Hillis-Steele inclusive scan over sc[1..128]
    for (int off = 1; off < 128; off <<= 1) {
        int v = 0;
        if (tid < 128 && tid >= off) v = sc[tid - off + 1];
        __syncthreads();
        if (tid < 128 && tid >= off) sc[tid + 1] += v;
        __syncthreads();
    }

    perm[sc[bin * 16 + wave] + wrank] = tid;
}

// ---------------- contiguous fold of 2 bilinear samples --------------------
// Sample valid iff coord in [0, LIM-1]; indices floor/floor+1 clamped to
// [0, LIM-1]. Output: contiguous [c0, c0+n), n in 1..4, zero-padded weights;
// invalid samples contribute 0. (Verified in round 8: absmax 0.0078.)
__device__ __forceinline__ void fold_dim(float s0, float step, int LIM,
                                         int& c0, int& n, float* w)
{
    float s[2] = { s0, s0 + step };
    int   fl[2]; float t[2]; bool val[2];
    int lo = 0x7fffffff, hi = -0x7fffffff;
#pragma unroll
    for (int k = 0; k < 2; ++k) {
        const float f = floorf(s[k]);
        fl[k]  = (int)f;
        t[k]   = s[k] - f;
        val[k] = (s[k] >= 0.0f && s[k] <= (float)(LIM - 1));
        if (val[k]) {
            lo = min(lo, fl[k]);
            hi = max(hi, min(fl[k] + 1, LIM - 1));
        }
    }
    w[0] = w[1] = w[2] = w[3] = 0.0f;
    if (lo > hi) {                     // no valid sample: degenerate, weight 0
        c0 = min(max(fl[0], 0), LIM - 1);
        n  = 1;
        return;
    }
    c0 = lo;
    n  = hi - lo + 1;                  // <= 4 (step <= 1.79)
#pragma unroll
    for (int k = 0; k < 2; ++k) {
        if (val[k]) {
            w[fl[k] - lo]                    += 1.0f - t[k];
            w[min(fl[k] + 1, LIM - 1) - lo]  += t[k];
        }
    }
}

// ---------------- kernel A2: per-pixel metadata (196 blocks x 256) ---------
__global__ __launch_bounds__(256) void pmeta_kernel(
    const float* __restrict__ boxes,
    const int*   __restrict__ box_inds,
    const int*   __restrict__ perm,
    int*         __restrict__ pm)
{
    const int p = blockIdx.x * 256 + threadIdx.x;
    if (p >= NBOX * NPIX) return;
    const int slot = p / NPIX;
    const int rem  = p - slot * NPIX;
    const int oy   = (rem * 37) >> 8;            // exact /7 for 0..48
    const int ox   = rem - oy * 7;

    const int b = perm[slot];
    const int n = box_inds[b];

    const float bx0 = boxes[b * 4 + 0] * SCALE;
    const float by0 = boxes[b * 4 + 1] * SCALE;
    const float bx1 = boxes[b * 4 + 2] * SCALE;
    const float by1 = boxes[b * 4 + 3] * SCALE;
    const float sw  = (bx1 - bx0) * (1.0f / 14.0f);
    const float sh  = (by1 - by0) * (1.0f / 14.0f);

    int r0, nr; float wr[4];
    fold_dim(by0 + sh * ((float)(oy * 2) + 0.5f) - 0.5f, sh, H_IN, r0, nr, wr);
    int c0, nc; float wc[4];
    fold_dim(bx0 + sw * ((float)(ox * 2) + 0.5f) - 0.5f, sw, W_IN, c0, nc, wc);

    int* q = pm + p * 12;
    q[0] = n * (H_IN * W_IN * C_IN) + r0 * (W_IN * C_IN) + c0 * C_IN;
    q[1] = (b * NPIX + rem) * C_IN;
    q[2] = (nr - 1) * 4 + (nc - 1);
    q[3] = 0;
    float* qf = (float*)q;
    qf[4] = wr[0] * 0.25f; qf[5] = wr[1] * 0.25f;
    qf[6] = wr[2] * 0.25f; qf[7] = wr[3] * 0.25f;
    qf[8] = wc[0]; qf[9] = wc[1]; qf[10] = wc[2]; qf[11] = wc[3];
}

// ---------------- gather: NR x NC corners at compile-time offsets ----------
template<int NR, int NC>
__device__ __forceinline__ f32x4 gather(const float* __restrict__ src,
                                        const float* wr, const float* wc)
{
    f32x4 v[NR][NC];
#pragma unroll
    for (int i = 0; i < NR; ++i)
#pragma unroll
        for (int j = 0; j < NC; ++j)
            v[i][j] = *(const f32x4*)(src + i * (W_IN * C_IN) + j * C_IN);

    f32x4 acc = {0.f, 0.f, 0.f, 0.f};
#pragma unroll
    for (int i = 0; i < NR; ++i)
#pragma unroll
        for (int j = 0; j < NC; ++j)
            acc += v[i][j] * (wr[i] * wc[j]);
    return acc;
}

// ---------------- kernel B: one wave per pixel -----------------------------
__global__ __launch_bounds__(256) void roi_align_kernel(
    const float* __restrict__ inputs,
    const int*   __restrict__ pm,
    float*       __restrict__ out)
{
    __shared__ int smeta[48];                    // 4 pixels x 12 dwords

    const int tid  = threadIdx.x;
    const int lane = tid & 63;
    const int wv   = tid >> 6;

    // XCD-chunked swizzle: grid = 12544 (div by 8); consecutive sorted pixels
    // land on the same XCD.
    const int nchunk = gridDim.x >> 3;
    const int lbid   = (blockIdx.x & 7) * nchunk + (blockIdx.x >> 3);
    const int p0     = lbid * 4;                 // first sorted pixel of block

    // one coalesced 192 B meta load for all 4 waves
    if (tid < 48) smeta[tid] = pm[p0 * 12 + tid];
    __syncthreads();

    const int* m = smeta + wv * 12;              // uniform LDS reads (broadcast)
    const int  base = m[0];
    const int  oute = m[1];
    const int  sel  = __builtin_amdgcn_readfirstlane(m[2]);
    const float* wr = (const float*)(m + 4);
    const float* wc = (const float*)(m + 8);

    const float* src = inputs + base + lane * 4;

    f32x4 acc;
    switch (sel) {
        case 0:  acc = gather<1, 1>(src, wr, wc); break;
        case 1:  acc = gather<1, 2>(src, wr, wc); break;
        case 2:  acc = gather<1, 3>(src, wr, wc); break;
        case 3:  acc = gather<1, 4>(src, wr, wc); break;
        case 4:  acc = gather<2, 1>(src, wr, wc); break;
        case 5:  acc = gather<2, 2>(src, wr, wc); break;
        case 6:  acc = gather<2, 3>(src, wr, wc); break;
        case 7:  acc = gather<2, 4>(src, wr, wc); break;
        case 8:  acc = gather<3, 1>(src, wr, wc); break;
        case 9:  acc = gather<3, 2>(src, wr, wc); break;
        case 10: acc = gather<3, 3>(src, wr, wc); break;
        case 11: acc = gather<3, 4>(src, wr, wc); break;
        case 12: acc = gather<4, 1>(src, wr, wc); break;
        case 13: acc = gather<4, 2>(src, wr, wc); break;
        case 14: acc = gather<4, 3>(src, wr, wc); break;
        default: acc = gather<4, 4>(src, wr, wc); break;
    }

    __builtin_nontemporal_store(acc, (f32x4*)(out + oute + lane * 4));
}

extern "C" void kernel_launch(void* const* d_in, const int* in_sizes, int n_in,
                              void* d_out, int out_size, void* d_ws, size_t ws_size,
                              hipStream_t stream) {
    const float* inputs   = (const float*)d_in[0];
    const float* boxes    = (const float*)d_in[1];
    const int*   box_inds = (const int*)d_in[2];
    float*       out      = (float*)d_out;

    int* perm = (int*)d_ws;
    int* pm   = (int*)((char*)d_ws + PMETA_OFF);

    sort_boxes_kernel<<<1, NBOX, 0, stream>>>(boxes, box_inds, perm);
    pmeta_kernel<<<196, 256, 0, stream>>>(boxes, box_inds, perm, pm);

    const int blocks = NBOX * NPIX / 4;          // 12544
    roi_align_kernel<<<blocks, 256, 0, stream>>>(inputs, pm, out);
}